// Round 4
// baseline (360.360 us; speedup 1.0000x reference)
//
#include <hip/hip_runtime.h>

#define LMAX   2048
#define NFFT   4096
#define DMODEL 512
#define NSTATE 64
#define NBATCH 16
#define NT     512
#define PI_D   3.14159265358979323846
#define REC_STRIDE 2050   // float4 records per channel-pair (2049 used, padded)

// ws layout:
//   [0, 32KB)              tw[4096] float2 = exp(-2*pi*i*j/4096)
//   [32KB, +8,396,800)     Kd records: 256 pairs x 2050 x float4 {K0re,K0im,K1re,K1im}
//   [next, +4MB)           Ktime[512][2048] float (time-domain K per channel)

// ---------- helpers ----------
__device__ __forceinline__ int fold(int a) { return a ^ ((a>>3)&7) ^ ((a>>6)&7); }
__device__ __forceinline__ int rev12(int t) {
  return ((t&7)<<9) | (((t>>3)&7)<<6) | (((t>>6)&7)<<3) | ((t>>9)&7);
}
__device__ __forceinline__ int rev11(int t) {   // mixed radix [8,8,8,4]
  return ((t&7)<<8) | (((t>>3)&7)<<5) | (((t>>6)&7)<<2) | ((t>>9)&3);
}
__device__ __forceinline__ float2 cmul(float2 a, float2 b) {
  return make_float2(a.x*b.x - a.y*b.y, a.x*b.y + a.y*b.x);
}
__device__ __forceinline__ float2 cmulc(float2 a, float2 b) {  // a * conj(b)
  return make_float2(a.x*b.x + a.y*b.y, a.y*b.x - a.x*b.y);
}
__device__ __forceinline__ float rcpf(float x) { return __builtin_amdgcn_rcpf(x); }

// 8-point DFT in registers. INV=false: y_j = sum_k x_k e^{-2pi i jk/8}.
template<bool INV>
__device__ __forceinline__ void bf8(float2 x[8]) {
  const float r2 = 0.70710678118654752f;
  float2 E0,E1,E2,E3,O0,O1,O2,O3;
  {
    float2 u0 = make_float2(x[0].x+x[4].x, x[0].y+x[4].y);
    float2 v0 = make_float2(x[0].x-x[4].x, x[0].y-x[4].y);
    float2 u1 = make_float2(x[2].x+x[6].x, x[2].y+x[6].y);
    float2 v1 = make_float2(x[2].x-x[6].x, x[2].y-x[6].y);
    E0 = make_float2(u0.x+u1.x, u0.y+u1.y);
    E2 = make_float2(u0.x-u1.x, u0.y-u1.y);
    if (!INV) { E1 = make_float2(v0.x+v1.y, v0.y-v1.x); E3 = make_float2(v0.x-v1.y, v0.y+v1.x); }
    else      { E1 = make_float2(v0.x-v1.y, v0.y+v1.x); E3 = make_float2(v0.x+v1.y, v0.y-v1.x); }
  }
  {
    float2 u0 = make_float2(x[1].x+x[5].x, x[1].y+x[5].y);
    float2 v0 = make_float2(x[1].x-x[5].x, x[1].y-x[5].y);
    float2 u1 = make_float2(x[3].x+x[7].x, x[3].y+x[7].y);
    float2 v1 = make_float2(x[3].x-x[7].x, x[3].y-x[7].y);
    O0 = make_float2(u0.x+u1.x, u0.y+u1.y);
    O2 = make_float2(u0.x-u1.x, u0.y-u1.y);
    if (!INV) { O1 = make_float2(v0.x+v1.y, v0.y-v1.x); O3 = make_float2(v0.x-v1.y, v0.y+v1.x); }
    else      { O1 = make_float2(v0.x-v1.y, v0.y+v1.x); O3 = make_float2(v0.x+v1.y, v0.y-v1.x); }
  }
  float2 o1 = (!INV) ? make_float2((O1.x+O1.y)*r2, (O1.y-O1.x)*r2)
                     : make_float2((O1.x-O1.y)*r2, (O1.y+O1.x)*r2);
  float2 o2 = (!INV) ? make_float2(O2.y, -O2.x) : make_float2(-O2.y, O2.x);
  float2 o3 = (!INV) ? make_float2((O3.y-O3.x)*r2, -(O3.x+O3.y)*r2)
                     : make_float2(-(O3.x+O3.y)*r2, (O3.x-O3.y)*r2);
  x[0] = make_float2(E0.x+O0.x, E0.y+O0.y);
  x[4] = make_float2(E0.x-O0.x, E0.y-O0.y);
  x[1] = make_float2(E1.x+o1.x, E1.y+o1.y);
  x[5] = make_float2(E1.x-o1.x, E1.y-o1.y);
  x[2] = make_float2(E2.x+o2.x, E2.y+o2.y);
  x[6] = make_float2(E2.x-o2.x, E2.y-o2.y);
  x[3] = make_float2(E3.x+o3.x, E3.y+o3.y);
  x[7] = make_float2(E3.x-o3.x, E3.y-o3.y);
}

__device__ __forceinline__ void bf4(float2 x[4]) {  // forward DFT4
  float2 u0 = make_float2(x[0].x+x[2].x, x[0].y+x[2].y);
  float2 v0 = make_float2(x[0].x-x[2].x, x[0].y-x[2].y);
  float2 u1 = make_float2(x[1].x+x[3].x, x[1].y+x[3].y);
  float2 v1 = make_float2(x[1].x-x[3].x, x[1].y-x[3].y);
  x[0] = make_float2(u0.x+u1.x, u0.y+u1.y);
  x[2] = make_float2(u0.x-u1.x, u0.y-u1.y);
  x[1] = make_float2(v0.x+v1.y, v0.y-v1.x);
  x[3] = make_float2(v0.x-v1.y, v0.y+v1.x);
}

// ---------- in-place 4096-pt FFT (fold-swizzled LDS), 512 threads ----------
// INV=false: DIF, natural in -> digit-reversed out (freq f at pos rev12(f)).
// INV=true : DIT, digit-reversed in -> natural out, unnormalized inverse.
template<bool INV>
__device__ void fft4096(float2* Z, const float2* __restrict__ tw, int tid) {
  int ad[8]; float2 x[8];
  if constexpr (!INV) {
    __syncthreads();
    { // NS=4096, stride 512
      const int p = tid;
      const int xb = ((p>>3)&7) ^ ((p>>6)&7);
      #pragma unroll
      for (int k=0;k<8;k++){ ad[k] = (p + (k<<9)) ^ xb; x[k] = Z[ad[k]]; }
      bf8<false>(x);
      Z[ad[0]] = x[0];
      #pragma unroll
      for (int j=1;j<8;j++) Z[ad[j]] = cmul(tw[p*j], x[j]);
    }
    __syncthreads();
    { // NS=512, stride 64
      const int p = tid & 63, B = tid >> 6;
      const int base = (B<<9) | p;
      const int xb = (p>>3)&7;
      #pragma unroll
      for (int k=0;k<8;k++){ ad[k] = ((base | (k<<6)) ^ xb) ^ k; x[k] = Z[ad[k]]; }
      bf8<false>(x);
      Z[ad[0]] = x[0];
      #pragma unroll
      for (int j=1;j<8;j++) Z[ad[j]] = cmul(tw[(p*j)<<3], x[j]);
    }
    __syncthreads();
    { // NS=64, stride 8
      const int p = tid & 7, B = tid >> 3;
      const int base = (B<<6) | p;
      const int xb = B & 7;
      #pragma unroll
      for (int k=0;k<8;k++){ ad[k] = ((base | (k<<3)) ^ xb) ^ k; x[k] = Z[ad[k]]; }
      bf8<false>(x);
      Z[ad[0]] = x[0];
      #pragma unroll
      for (int j=1;j<8;j++) Z[ad[j]] = cmul(tw[(p*j)<<6], x[j]);
    }
    __syncthreads();
    { // NS=8, stride 1, no twiddles
      const int B = tid;
      const int xb = (B&7) ^ ((B>>3)&7);
      #pragma unroll
      for (int k=0;k<8;k++){ ad[k] = (B<<3) | (k ^ xb); x[k] = Z[ad[k]]; }
      bf8<false>(x);
      #pragma unroll
      for (int j=0;j<8;j++) Z[ad[j]] = x[j];
    }
    __syncthreads();
  } else {
    __syncthreads();
    { // NS=8
      const int B = tid;
      const int xb = (B&7) ^ ((B>>3)&7);
      #pragma unroll
      for (int k=0;k<8;k++){ ad[k] = (B<<3) | (k ^ xb); x[k] = Z[ad[k]]; }
      bf8<true>(x);
      #pragma unroll
      for (int j=0;j<8;j++) Z[ad[j]] = x[j];
    }
    __syncthreads();
    { // NS=64: input twiddle conj(tw[64 p k])
      const int p = tid & 7, B = tid >> 3;
      const int base = (B<<6) | p;
      const int xb = B & 7;
      #pragma unroll
      for (int k=0;k<8;k++){ ad[k] = ((base | (k<<3)) ^ xb) ^ k; x[k] = Z[ad[k]]; }
      #pragma unroll
      for (int k=1;k<8;k++) x[k] = cmulc(x[k], tw[(p*k)<<6]);
      bf8<true>(x);
      #pragma unroll
      for (int j=0;j<8;j++) Z[ad[j]] = x[j];
    }
    __syncthreads();
    { // NS=512
      const int p = tid & 63, B = tid >> 6;
      const int base = (B<<9) | p;
      const int xb = (p>>3)&7;
      #pragma unroll
      for (int k=0;k<8;k++){ ad[k] = ((base | (k<<6)) ^ xb) ^ k; x[k] = Z[ad[k]]; }
      #pragma unroll
      for (int k=1;k<8;k++) x[k] = cmulc(x[k], tw[(p*k)<<3]);
      bf8<true>(x);
      #pragma unroll
      for (int j=0;j<8;j++) Z[ad[j]] = x[j];
    }
    __syncthreads();
    { // NS=4096
      const int p = tid;
      const int xb = ((p>>3)&7) ^ ((p>>6)&7);
      #pragma unroll
      for (int k=0;k<8;k++){ ad[k] = (p + (k<<9)) ^ xb; x[k] = Z[ad[k]]; }
      #pragma unroll
      for (int k=1;k<8;k++) x[k] = cmulc(x[k], tw[p*k]);
      bf8<true>(x);
      #pragma unroll
      for (int j=0;j<8;j++) Z[ad[j]] = x[j];
    }
    __syncthreads();
  }
}

// ---------- in-place forward DIF 2048 (radices 8,8,8,4), 512 threads ----------
// Natural in -> out with freq f at pos rev11(f).
__device__ void dif2048(float2* Z, const float2* __restrict__ tw, int tid) {
  int ad[8]; float2 x[8];
  __syncthreads();
  if (tid < 256) { // NS=2048, stride 256
    const int p = tid;
    const int xb = ((p>>3)&7) ^ ((p>>6)&3);
    #pragma unroll
    for (int k=0;k<8;k++){ ad[k] = ((p | (k<<8)) ^ xb) ^ ((k&1)<<2); x[k] = Z[ad[k]]; }
    bf8<false>(x);
    Z[ad[0]] = x[0];
    #pragma unroll
    for (int j=1;j<8;j++) Z[ad[j]] = cmul(tw[(p*j)<<1], x[j]);
  }
  __syncthreads();
  if (tid < 256) { // NS=256, stride 32
    const int p = tid & 31, B = tid >> 5;
    const int base = (B<<8) | p;
    const int xb = ((p>>3)&3) ^ ((B&1)<<2);
    #pragma unroll
    for (int k=0;k<8;k++){ ad[k] = ((base | (k<<5)) ^ xb) ^ (((k&1)<<2) | (k>>1)); x[k] = Z[ad[k]]; }
    bf8<false>(x);
    Z[ad[0]] = x[0];
    #pragma unroll
    for (int j=1;j<8;j++) Z[ad[j]] = cmul(tw[(p*j)<<4], x[j]);
  }
  __syncthreads();
  if (tid < 256) { // NS=32, stride 4
    const int p = tid & 3, B = tid >> 2;
    const int base = (B<<5) | p;
    const int xb = ((B&1)<<2) ^ ((B>>1)&7);
    #pragma unroll
    for (int k=0;k<8;k++){ ad[k] = ((base | (k<<2)) ^ xb) ^ (k>>1); x[k] = Z[ad[k]]; }
    bf8<false>(x);
    Z[ad[0]] = x[0];
    #pragma unroll
    for (int j=1;j<8;j++) Z[ad[j]] = cmul(tw[(p*j)<<7], x[j]);
  }
  __syncthreads();
  { // NS=4 radix-4, 512 butterflies, no twiddles
    const int B = tid;
    const int xb = ((B>>1)&7) ^ ((B>>4)&7);
    float2 y[4]; int a4[4];
    #pragma unroll
    for (int j=0;j<4;j++){ a4[j] = ((B<<2) | j) ^ xb; y[j] = Z[a4[j]]; }
    bf4(y);
    #pragma unroll
    for (int j=0;j<4;j++) Z[a4[j]] = y[j];
  }
  __syncthreads();
}

// ---------- kernels ----------
__global__ void twiddle_init(float2* tw) {
  int j = blockIdx.x * blockDim.x + threadIdx.x;
  if (j < NFFT) {
    double ang = -2.0 * PI_D * (double)j / (double)NFFT;
    double s, c;
    sincos(ang, &s, &c);
    tw[j] = make_float2((float)c, (float)s);
  }
}

// Phase A: one block per channel d. Cauchy at 2048 roots -> in-place DIF-2048
// -> Ktime[d][k] = Re(spec at rev11(k))/2048  (== reference ifft+reorder+.real)
__global__ __launch_bounds__(NT) void s4_kernelA(
    const float* __restrict__ p_ri, const float* __restrict__ q_ri,
    const float* __restrict__ lam_ri, const float* __restrict__ B_ri,
    const float* __restrict__ Ct_ri, const float* __restrict__ log_step,
    const float2* __restrict__ tw, float* __restrict__ Ktime)
{
  __shared__ float2 Z[2048 + 5*64];
  float2* Wg = Z + 2048;            // lam | w00 | w01 | w10 | w11, 64 each
  const int d = blockIdx.x;
  const int tid = threadIdx.x;

  if (tid < NSTATE) {
    const int n = tid;
    float2 la = make_float2(lam_ri[2*n], lam_ri[2*n+1]);
    float2 pp = make_float2(p_ri[2*n],  p_ri[2*n+1]);
    float2 qq = make_float2(q_ri[2*n],  q_ri[2*n+1]);
    float2 Bv = make_float2(B_ri[(d*NSTATE+n)*2],  B_ri[(d*NSTATE+n)*2+1]);
    float2 Cv = make_float2(Ct_ri[(d*NSTATE+n)*2], Ct_ri[(d*NSTATE+n)*2+1]);
    Wg[n] = la;
    // a0 = conj(Ct), a1 = conj(q), b0 = B, b1 = p
    Wg[64 +n] = make_float2(Cv.x*Bv.x + Cv.y*Bv.y, Cv.x*Bv.y - Cv.y*Bv.x);
    Wg[128+n] = make_float2(Cv.x*pp.x + Cv.y*pp.y, Cv.x*pp.y - Cv.y*pp.x);
    Wg[192+n] = make_float2(qq.x*Bv.x + qq.y*Bv.y, qq.x*Bv.y - qq.y*Bv.x);
    Wg[256+n] = make_float2(qq.x*pp.x + qq.y*pp.y, qq.x*pp.y - qq.y*pp.x);
  }
  __syncthreads();

  const float tos = 2.0f * rcpf(expf(log_step[d]));
  float2 g[4], cc[4];
  #pragma unroll
  for (int il=0; il<4; ++il) {
    const int l = tid + (il<<9);
    float theta = (float)(2.0 * PI_D / (double)LMAX) * (float)l;
    float si, co;
    sincosf(theta, &si, &co);
    float dx = 1.f + co, dy = si;
    float inv = rcpf(dx*dx + dy*dy);
    cc[il] = make_float2(2.f*dx*inv, -2.f*dy*inv);
    float nx = 1.f - co, ny = -si;
    g[il] = make_float2(tos*(nx*dx + ny*dy)*inv, tos*(ny*dx - nx*dy)*inv);
  }
  float2 a00[4], a01[4], a10[4], a11[4];
  #pragma unroll
  for (int il=0; il<4; ++il) { a00[il]=make_float2(0,0); a01[il]=make_float2(0,0);
                               a10[il]=make_float2(0,0); a11[il]=make_float2(0,0); }
  for (int nc = 0; nc < NSTATE; nc += 4) {
    float2 la[4], w0[4], w1[4], w2[4], w3[4];
    #pragma unroll
    for (int j=0;j<4;j++) {
      la[j] = Wg[nc+j];      w0[j] = Wg[64+nc+j];  w1[j] = Wg[128+nc+j];
      w2[j] = Wg[192+nc+j];  w3[j] = Wg[256+nc+j];
    }
    #pragma unroll
    for (int il=0; il<4; ++il) {
      #pragma unroll
      for (int j=0;j<4;j++) {
        float rr = g[il].x - la[j].x, ri = g[il].y - la[j].y;
        float rinv = rcpf(rr*rr + ri*ri);
        float rx = rr*rinv, ry = -ri*rinv;
        a00[il].x += w0[j].x*rx - w0[j].y*ry; a00[il].y += w0[j].x*ry + w0[j].y*rx;
        a01[il].x += w1[j].x*rx - w1[j].y*ry; a01[il].y += w1[j].x*ry + w1[j].y*rx;
        a10[il].x += w2[j].x*rx - w2[j].y*ry; a10[il].y += w2[j].x*ry + w2[j].y*rx;
        a11[il].x += w3[j].x*rx - w3[j].y*ry; a11[il].y += w3[j].x*ry + w3[j].y*rx;
      }
    }
  }
  #pragma unroll
  for (int il=0; il<4; ++il) {
    const int l = tid + (il<<9);
    float2 s1 = make_float2(1.f + a11[il].x, a11[il].y);
    float sinv = rcpf(s1.x*s1.x + s1.y*s1.y);
    float2 t = cmul(a01[il], a10[il]);
    float2 tdiv = make_float2((t.x*s1.x + t.y*s1.y)*sinv, (t.y*s1.x - t.x*s1.y)*sinv);
    Z[fold(l)] = cmul(cc[il], make_float2(a00[il].x - tdiv.x, a00[il].y - tdiv.y));
  }

  dif2048(Z, tw, tid);

  #pragma unroll
  for (int il=0; il<4; ++il) {
    const int kk = tid + (il<<9);
    Ktime[(size_t)d * LMAX + kk] = Z[fold(rev11(kk))].x * (1.0f / LMAX);
  }
}

// Phase B: one block per channel pair. Pack K0+i*K1 -> DIF-4096 -> Hermitian
// unpack into paired records {K0[t],K1[t]} (t = 0..2048), f>2048 via conj.
__global__ __launch_bounds__(NT) void s4_kernelB(
    const float* __restrict__ Ktime, const float2* __restrict__ tw,
    float4* __restrict__ Kd)
{
  __shared__ float2 Z[NFFT];
  const int dp = blockIdx.x;
  const int tid = threadIdx.x;
  const float* K0p = Ktime + (size_t)(2*dp) * LMAX;
  const float* K1p = K0p + LMAX;
  #pragma unroll
  for (int il=0; il<4; ++il) {
    const int kk = tid + (il<<9);
    Z[fold(kk)] = make_float2(K0p[kk], K1p[kk]);
    Z[fold(LMAX + kk)] = make_float2(0.f, 0.f);
  }
  fft4096<false>(Z, tw, tid);
  float4* rec = Kd + (size_t)dp * REC_STRIDE;
  #pragma unroll
  for (int it=0; it<5; ++it) {
    int t = tid + (it<<9);
    if (it == 4) { if (tid != 0) break; t = 2048; }
    const int j1 = fold(rev12(t));
    const int j2 = fold(rev12((NFFT - t) & (NFFT-1)));
    float2 zf = Z[j1], zr = Z[j2];
    float k0x = 0.5f*(zf.x + zr.x), k0y = 0.5f*(zf.y - zr.y);
    float dx = zf.x - zr.x, dy = zf.y + zr.y;
    rec[t] = make_float4(k0x, k0y, 0.5f*dy, -0.5f*dx);
  }
}

// Conv: one block per (batch, channel pair), XCD-swizzled. Pack 2 real
// channels -> DIF-4096 -> paired pointwise in scrambled domain -> DIT-4096
// (natural out) -> + D*u.
__global__ __launch_bounds__(NT) void s4_conv(
    const float* __restrict__ u, const float* __restrict__ Dp,
    const float2* __restrict__ tw, const float4* __restrict__ Kd,
    float* __restrict__ out)
{
  __shared__ float2 Z[NFFT];
  const int bxr = blockIdx.x;
  const int dp  = (bxr & 7) * 32 + (bxr >> 3);   // XCD c owns dp [c*32,(c+1)*32)
  const int b   = blockIdx.y;
  const int d0  = dp * 2;
  const int tid = threadIdx.x;

  float2 ur[4];
  const float* ubase = u + ((size_t)b * LMAX) * DMODEL + d0;
  #pragma unroll
  for (int k=0; k<4; ++k) {
    const int l = tid + (k<<9);
    float2 v = *(const float2*)(ubase + (size_t)l * DMODEL);
    ur[k] = v;
    Z[fold(l)] = v;                              // z = u[d0] + i*u[d0+1]
    Z[fold(LMAX + l)] = make_float2(0.f, 0.f);
  }

  fft4096<false>(Z, tw, tid);

  const float4* rec = Kd + (size_t)dp * REC_STRIDE;
  #pragma unroll
  for (int it=0; it<5; ++it) {
    int t = tid + (it<<9);
    if (it == 4) { if (tid != 0) break; t = 2048; }
    const int j1 = fold(rev12(t));
    const int j2 = fold(rev12((NFFT - t) & (NFFT-1)));
    float2 zf = Z[j1], zr = Z[j2];
    float4 r4 = rec[t];
    float2 K0 = make_float2(r4.x, r4.y), K1 = make_float2(r4.z, r4.w);
    // U0 = (zf + conj zr)/2 ; U1 = -i/2 (zf - conj zr)
    float2 u0 = make_float2(0.5f*(zf.x + zr.x), 0.5f*(zf.y - zr.y));
    float du_x = zf.x - zr.x, du_y = zf.y + zr.y;
    float2 u1 = make_float2(0.5f*du_y, -0.5f*du_x);
    float2 P = cmul(u0, K0);
    float2 Q = cmul(u1, K1);
    Z[j1] = make_float2(P.x - Q.y, P.y + Q.x);   // W[f]  = P + iQ
    Z[j2] = make_float2(P.x + Q.y, Q.x - P.y);   // W[-f] = conj(P - iQ)
  }

  fft4096<true>(Z, tw, tid);

  const float D0 = Dp[d0], D1 = Dp[d0 + 1];
  float* obase = out + ((size_t)b * LMAX) * DMODEL + d0;
  const float scale = 1.0f / NFFT;
  #pragma unroll
  for (int k=0; k<4; ++k) {
    const int l = tid + (k<<9);
    float2 w = Z[fold(l)];
    float2 o = make_float2(w.x*scale + D0*ur[k].x, w.y*scale + D1*ur[k].y);
    *(float2*)(obase + (size_t)l * DMODEL) = o;
  }
}

extern "C" void kernel_launch(void* const* d_in, const int* in_sizes, int n_in,
                              void* d_out, int out_size, void* d_ws, size_t ws_size,
                              hipStream_t stream) {
  const float* u        = (const float*)d_in[0];
  const float* p_ri     = (const float*)d_in[1];
  const float* q_ri     = (const float*)d_in[2];
  const float* lam_ri   = (const float*)d_in[3];
  const float* B_ri     = (const float*)d_in[4];
  const float* Ct_ri    = (const float*)d_in[5];
  const float* Dp       = (const float*)d_in[6];
  const float* log_step = (const float*)d_in[7];
  float* out = (float*)d_out;

  char* wsb = (char*)d_ws;
  float2* tw    = (float2*)wsb;                                  // 32 KB
  float4* Kd    = (float4*)(wsb + NFFT * sizeof(float2));        // 8,396,800 B
  float*  Ktime = (float*)(wsb + NFFT * sizeof(float2)
                               + (size_t)256 * REC_STRIDE * sizeof(float4)); // 4 MB

  twiddle_init<<<16, 256, 0, stream>>>(tw);
  s4_kernelA<<<DMODEL, NT, 0, stream>>>(p_ri, q_ri, lam_ri, B_ri, Ct_ri,
                                        log_step, tw, Ktime);
  s4_kernelB<<<DMODEL/2, NT, 0, stream>>>(Ktime, tw, Kd);
  s4_conv<<<dim3(DMODEL/2, NBATCH), NT, 0, stream>>>(u, Dp, tw, Kd, out);
}

// Round 5
// 332.252 us; speedup vs baseline: 1.0846x; 1.0846x over previous
//
#include <hip/hip_runtime.h>

#define LMAX   2048
#define NFFT   4096
#define DMODEL 512
#define NSTATE 64
#define NBATCH 16
#define PI_D   3.14159265358979323846
#define REC_STRIDE 2050   // float4 records per channel-pair (2049 used, padded)

// LDS pad: +1 float2 every 16 -> all Stockham radix-8 stage writes become
// <=2-way bank-pair conflicts (free). P(4095)=4350 -> buffer 4352 float2.
#define PAD(e) ((e) + ((e) >> 4))

// ws layout:
//   [0, 32KB)            tw[4096] float2 = exp(-2*pi*i*j/4096)
//   [32KB, +8,396,800)   Kd records: 256 pairs x 2050 float4 {K0re,K0im,K1re,K1im}
//                        (ALIASED early as atr[512][2048] float2 = 8 MB: atr is
//                         dead before pairB writes Kd)
//   [next, +4MB)         Ktime[512][2048] float

__device__ __forceinline__ float2 cmul(float2 a, float2 b) {
  return make_float2(a.x*b.x - a.y*b.y, a.x*b.y + a.y*b.x);
}
__device__ __forceinline__ float rcpf(float x) { return __builtin_amdgcn_rcpf(x); }

// 8-point DFT in registers. INV=false: y_j = sum_k x_k e^{-2pi i jk/8}.
template<bool INV>
__device__ __forceinline__ void bf8(float2 x[8]) {
  const float r2 = 0.70710678118654752f;
  float2 E0,E1,E2,E3,O0,O1,O2,O3;
  {
    float2 u0 = make_float2(x[0].x+x[4].x, x[0].y+x[4].y);
    float2 v0 = make_float2(x[0].x-x[4].x, x[0].y-x[4].y);
    float2 u1 = make_float2(x[2].x+x[6].x, x[2].y+x[6].y);
    float2 v1 = make_float2(x[2].x-x[6].x, x[2].y-x[6].y);
    E0 = make_float2(u0.x+u1.x, u0.y+u1.y);
    E2 = make_float2(u0.x-u1.x, u0.y-u1.y);
    if (!INV) { E1 = make_float2(v0.x+v1.y, v0.y-v1.x); E3 = make_float2(v0.x-v1.y, v0.y+v1.x); }
    else      { E1 = make_float2(v0.x-v1.y, v0.y+v1.x); E3 = make_float2(v0.x+v1.y, v0.y-v1.x); }
  }
  {
    float2 u0 = make_float2(x[1].x+x[5].x, x[1].y+x[5].y);
    float2 v0 = make_float2(x[1].x-x[5].x, x[1].y-x[5].y);
    float2 u1 = make_float2(x[3].x+x[7].x, x[3].y+x[7].y);
    float2 v1 = make_float2(x[3].x-x[7].x, x[3].y-x[7].y);
    O0 = make_float2(u0.x+u1.x, u0.y+u1.y);
    O2 = make_float2(u0.x-u1.x, u0.y-u1.y);
    if (!INV) { O1 = make_float2(v0.x+v1.y, v0.y-v1.x); O3 = make_float2(v0.x-v1.y, v0.y+v1.x); }
    else      { O1 = make_float2(v0.x-v1.y, v0.y+v1.x); O3 = make_float2(v0.x+v1.y, v0.y-v1.x); }
  }
  float2 o1 = (!INV) ? make_float2((O1.x+O1.y)*r2, (O1.y-O1.x)*r2)
                     : make_float2((O1.x-O1.y)*r2, (O1.y+O1.x)*r2);
  float2 o2 = (!INV) ? make_float2(O2.y, -O2.x) : make_float2(-O2.y, O2.x);
  float2 o3 = (!INV) ? make_float2((O3.y-O3.x)*r2, -(O3.x+O3.y)*r2)
                     : make_float2(-(O3.x+O3.y)*r2, (O3.x-O3.y)*r2);
  x[0] = make_float2(E0.x+O0.x, E0.y+O0.y);
  x[4] = make_float2(E0.x-O0.x, E0.y-O0.y);
  x[1] = make_float2(E1.x+o1.x, E1.y+o1.y);
  x[5] = make_float2(E1.x-o1.x, E1.y-o1.y);
  x[2] = make_float2(E2.x+o2.x, E2.y+o2.y);
  x[6] = make_float2(E2.x-o2.x, E2.y-o2.y);
  x[3] = make_float2(E3.x+o3.x, E3.y+o3.y);
  x[7] = make_float2(E3.x-o3.x, E3.y-o3.y);
}

__device__ __forceinline__ void bf4(float2 x[4]) {  // forward DFT4
  float2 u0 = make_float2(x[0].x+x[2].x, x[0].y+x[2].y);
  float2 v0 = make_float2(x[0].x-x[2].x, x[0].y-x[2].y);
  float2 u1 = make_float2(x[1].x+x[3].x, x[1].y+x[3].y);
  float2 v1 = make_float2(x[1].x-x[3].x, x[1].y-x[3].y);
  x[0] = make_float2(u0.x+u1.x, u0.y+u1.y);
  x[2] = make_float2(u0.x-u1.x, u0.y-u1.y);
  x[1] = make_float2(v0.x+v1.y, v0.y-v1.x);
  x[3] = make_float2(v0.x-v1.y, v0.y+v1.x);
}

// Stockham ping-pong FFT in LDS, radix-8 stages (+ radix-4 tail for LOGN=11,
// forward only). Self-sorting: natural in -> natural out. All LDS indices
// PAD()ed. Twiddles from GLOBAL 4096-entry table (L1-resident). Returns the
// result buffer (== src for LOGN in {11,12}: 4 swaps).
template<int LOGN, bool INV, int NT>
__device__ float2* fft_lds(float2* src, float2* dst, const float2* __restrict__ tw, int tid) {
  constexpr int N = 1 << LOGN;
  constexpr int NS8 = LOGN / 3;
  constexpr int TSH = 12 - LOGN;
  int s = 1;
  #pragma unroll
  for (int st = 0; st < NS8; ++st) {
    __syncthreads();
    for (int i = tid; i < (N >> 3); i += NT) {
      const int q  = i & (s - 1);
      const int ps = i - q;                 // p*s
      float2 x[8];
      #pragma unroll
      for (int k = 0; k < 8; ++k) x[k] = src[PAD(i + k * (N >> 3))];
      bf8<INV>(x);
      const int idx1 = ps << TSH;           // twiddle W_4096^{idx1*j}
      const int ob   = q + (ps << 3);
      dst[PAD(ob)] = x[0];
      #pragma unroll
      for (int j = 1; j < 8; ++j) {
        float2 w = tw[j * idx1];
        if (INV) w.y = -w.y;
        dst[PAD(ob + j * s)] = cmul(w, x[j]);
      }
    }
    s <<= 3;
    float2* t = src; src = dst; dst = t;
  }
  if constexpr (LOGN % 3 == 2) {            // radix-4 tail (s=512, trivial tw)
    __syncthreads();
    for (int i = tid; i < (N >> 2); i += NT) {
      const int q  = i & (s - 1);
      const int ps = i - q;                 // == 0 here, twiddles trivial
      float2 x[4];
      #pragma unroll
      for (int k = 0; k < 4; ++k) x[k] = src[PAD(i + k * (N >> 2))];
      bf4(x);
      const int ob = q + (ps << 2);
      #pragma unroll
      for (int j = 0; j < 4; ++j) dst[PAD(ob + j * s)] = x[j];
    }
    float2* t = src; src = dst; dst = t;
  }
  __syncthreads();
  return src;
}

__global__ void twiddle_init(float2* tw) {
  int j = blockIdx.x * blockDim.x + threadIdx.x;
  if (j < NFFT) {
    double ang = -2.0 * PI_D * (double)j / (double)NFFT;
    double s, c;
    sincos(ang, &s, &c);
    tw[j] = make_float2((float)c, (float)s);
  }
}

// Cauchy kernel evaluation, high-occupancy: grid (512 d, 8 lchunk) x 256 thr,
// one l-point per thread, tiny LDS, 4-deep weight prefetch for ILP.
// Writes at_roots[d][l] (float2) to ws.
__global__ __launch_bounds__(256) void s4_cauchy(
    const float* __restrict__ p_ri, const float* __restrict__ q_ri,
    const float* __restrict__ lam_ri, const float* __restrict__ B_ri,
    const float* __restrict__ Ct_ri, const float* __restrict__ log_step,
    float2* __restrict__ atr)
{
  __shared__ float2 Wg[5*64];   // lam | w00 | w01 | w10 | w11
  const int d = blockIdx.x;
  const int tid = threadIdx.x;
  const int l = blockIdx.y * 256 + tid;

  if (tid < NSTATE) {
    const int n = tid;
    float2 la = make_float2(lam_ri[2*n], lam_ri[2*n+1]);
    float2 pp = make_float2(p_ri[2*n],  p_ri[2*n+1]);
    float2 qq = make_float2(q_ri[2*n],  q_ri[2*n+1]);
    float2 Bv = make_float2(B_ri[(d*NSTATE+n)*2],  B_ri[(d*NSTATE+n)*2+1]);
    float2 Cv = make_float2(Ct_ri[(d*NSTATE+n)*2], Ct_ri[(d*NSTATE+n)*2+1]);
    Wg[n] = la;
    // a0 = conj(Ct), a1 = conj(q), b0 = B, b1 = p
    Wg[64 +n] = make_float2(Cv.x*Bv.x + Cv.y*Bv.y, Cv.x*Bv.y - Cv.y*Bv.x);
    Wg[128+n] = make_float2(Cv.x*pp.x + Cv.y*pp.y, Cv.x*pp.y - Cv.y*pp.x);
    Wg[192+n] = make_float2(qq.x*Bv.x + qq.y*Bv.y, qq.x*Bv.y - qq.y*Bv.x);
    Wg[256+n] = make_float2(qq.x*pp.x + qq.y*pp.y, qq.x*pp.y - qq.y*pp.x);
  }
  __syncthreads();

  const float tos = 2.0f * rcpf(expf(log_step[d]));
  float theta = (float)(2.0 * PI_D / (double)LMAX) * (float)l;
  float si, co;
  sincosf(theta, &si, &co);
  float dx = 1.f + co, dy = si;
  float inv = rcpf(dx*dx + dy*dy);
  float2 cc = make_float2(2.f*dx*inv, -2.f*dy*inv);
  float nx = 1.f - co, ny = -si;
  float2 g = make_float2(tos*(nx*dx + ny*dy)*inv, tos*(ny*dx - nx*dy)*inv);

  float2 a00 = {0,0}, a01 = {0,0}, a10 = {0,0}, a11 = {0,0};
  for (int nc = 0; nc < NSTATE; nc += 4) {
    float2 la[4], w0[4], w1[4], w2[4], w3[4];
    #pragma unroll
    for (int j=0;j<4;j++) {
      la[j] = Wg[nc+j];      w0[j] = Wg[64+nc+j];  w1[j] = Wg[128+nc+j];
      w2[j] = Wg[192+nc+j];  w3[j] = Wg[256+nc+j];
    }
    #pragma unroll
    for (int j=0;j<4;j++) {
      float rr = g.x - la[j].x, ri = g.y - la[j].y;
      float rinv = rcpf(rr*rr + ri*ri);
      float rx = rr*rinv, ry = -ri*rinv;
      a00.x += w0[j].x*rx - w0[j].y*ry; a00.y += w0[j].x*ry + w0[j].y*rx;
      a01.x += w1[j].x*rx - w1[j].y*ry; a01.y += w1[j].x*ry + w1[j].y*rx;
      a10.x += w2[j].x*rx - w2[j].y*ry; a10.y += w2[j].x*ry + w2[j].y*rx;
      a11.x += w3[j].x*rx - w3[j].y*ry; a11.y += w3[j].x*ry + w3[j].y*rx;
    }
  }
  float2 s1 = make_float2(1.f + a11.x, a11.y);
  float sinv = rcpf(s1.x*s1.x + s1.y*s1.y);
  float2 t = cmul(a01, a10);
  float2 tdiv = make_float2((t.x*s1.x + t.y*s1.y)*sinv, (t.y*s1.x - t.x*s1.y)*sinv);
  atr[(size_t)d * LMAX + l] = cmul(cc, make_float2(a00.x - tdiv.x, a00.y - tdiv.y));
}

// Per-channel 2048-pt forward FFT of at_roots:
// Ktime[d][k] = Re(DFT_2048(atr[d])[k]) / 2048 (== reference ifft+reorder+.real)
__global__ __launch_bounds__(256) void s4_fftK(
    const float2* __restrict__ atr, const float2* __restrict__ tw,
    float* __restrict__ Ktime)
{
  __shared__ float2 ZA[PAD(LMAX-1)+2], ZB[PAD(LMAX-1)+2];
  const int d = blockIdx.x;
  const int tid = threadIdx.x;
  const float2* src = atr + (size_t)d * LMAX;
  #pragma unroll
  for (int k=0; k<8; ++k) { const int l = tid + (k<<8); ZA[PAD(l)] = src[l]; }
  float2* Z = fft_lds<11, false, 256>(ZA, ZB, tw, tid);
  #pragma unroll
  for (int k=0; k<8; ++k) {
    const int kk = tid + (k<<8);
    Ktime[(size_t)d * LMAX + kk] = Z[PAD(kk)].x * (1.0f / LMAX);
  }
}

// Per channel-pair: pack K0 + i*K1 -> forward 4096 FFT (natural order) ->
// Hermitian unpack into paired records {K0[t],K1[t]}, t = 0..2048.
__global__ __launch_bounds__(512) void s4_pairB(
    const float* __restrict__ Ktime, const float2* __restrict__ tw,
    float4* __restrict__ Kd)
{
  __shared__ float2 ZA[PAD(NFFT-1)+2], ZB[PAD(NFFT-1)+2];
  const int dp = blockIdx.x;
  const int tid = threadIdx.x;
  const float* K0p = Ktime + (size_t)(2*dp) * LMAX;
  const float* K1p = K0p + LMAX;
  #pragma unroll
  for (int il=0; il<4; ++il) {
    const int kk = tid + (il<<9);
    ZA[PAD(kk)] = make_float2(K0p[kk], K1p[kk]);
    ZA[PAD(LMAX + kk)] = make_float2(0.f, 0.f);
  }
  float2* Z = fft_lds<12, false, 512>(ZA, ZB, tw, tid);
  float4* rec = Kd + (size_t)dp * REC_STRIDE;
  #pragma unroll
  for (int it=0; it<5; ++it) {
    int t = tid + (it<<9);
    if (it == 4) { if (tid != 0) break; t = 2048; }
    float2 zf = Z[PAD(t)];
    float2 zr = Z[PAD((NFFT - t) & (NFFT-1))];
    float k0x = 0.5f*(zf.x + zr.x), k0y = 0.5f*(zf.y - zr.y);
    float dx = zf.x - zr.x, dy = zf.y + zr.y;
    rec[t] = make_float4(k0x, k0y, 0.5f*dy, -0.5f*dx);
  }
}

// Conv: one block per (batch, channel pair), XCD-swizzled. Pack 2 real
// channels -> fwd 4096 FFT -> Hermitian-paired pointwise -> inv FFT -> +D*u.
__global__ __launch_bounds__(512) void s4_conv(
    const float* __restrict__ u, const float* __restrict__ Dp,
    const float2* __restrict__ tw, const float4* __restrict__ Kd,
    float* __restrict__ out)
{
  __shared__ float2 ZA[PAD(NFFT-1)+2], ZB[PAD(NFFT-1)+2];
  const int bxr = blockIdx.x;
  const int dp  = (bxr & 7) * 32 + (bxr >> 3);   // XCD c owns dp [c*32,(c+1)*32)
  const int b   = blockIdx.y;
  const int d0  = dp * 2;
  const int tid = threadIdx.x;

  float2 ur[4];
  const float* ubase = u + ((size_t)b * LMAX) * DMODEL + d0;
  #pragma unroll
  for (int k=0; k<4; ++k) {
    const int l = tid + (k<<9);
    float2 v = *(const float2*)(ubase + (size_t)l * DMODEL);
    ur[k] = v;
    ZA[PAD(l)] = v;                              // z = u[d0] + i*u[d0+1]
    ZA[PAD(LMAX + l)] = make_float2(0.f, 0.f);
  }

  float2* Z = fft_lds<12, false, 512>(ZA, ZB, tw, tid);   // == ZA

  const float4* rec = Kd + (size_t)dp * REC_STRIDE;
  #pragma unroll
  for (int it=0; it<5; ++it) {
    int t = tid + (it<<9);
    if (it == 4) { if (tid != 0) break; t = 2048; }
    const int j1 = PAD(t);
    const int j2 = PAD((NFFT - t) & (NFFT-1));
    float2 zf = Z[j1], zr = Z[j2];
    float4 r4 = rec[t];
    float2 K0 = make_float2(r4.x, r4.y), K1 = make_float2(r4.z, r4.w);
    // U0 = (zf + conj zr)/2 ; U1 = -i/2 (zf - conj zr)
    float2 u0 = make_float2(0.5f*(zf.x + zr.x), 0.5f*(zf.y - zr.y));
    float du_x = zf.x - zr.x, du_y = zf.y + zr.y;
    float2 u1 = make_float2(0.5f*du_y, -0.5f*du_x);
    float2 P = cmul(u0, K0);
    float2 Q = cmul(u1, K1);
    Z[j1] = make_float2(P.x - Q.y, P.y + Q.x);   // W[f]  = P + iQ
    Z[j2] = make_float2(P.x + Q.y, Q.x - P.y);   // W[-f] = conj(P - iQ)
  }

  float2* W = fft_lds<12, true, 512>(Z, (Z == ZA) ? ZB : ZA, tw, tid);

  const float D0 = Dp[d0], D1 = Dp[d0 + 1];
  float* obase = out + ((size_t)b * LMAX) * DMODEL + d0;
  const float scale = 1.0f / NFFT;
  #pragma unroll
  for (int k=0; k<4; ++k) {
    const int l = tid + (k<<9);
    float2 w = W[PAD(l)];
    float2 o = make_float2(w.x*scale + D0*ur[k].x, w.y*scale + D1*ur[k].y);
    *(float2*)(obase + (size_t)l * DMODEL) = o;
  }
}

extern "C" void kernel_launch(void* const* d_in, const int* in_sizes, int n_in,
                              void* d_out, int out_size, void* d_ws, size_t ws_size,
                              hipStream_t stream) {
  const float* u        = (const float*)d_in[0];
  const float* p_ri     = (const float*)d_in[1];
  const float* q_ri     = (const float*)d_in[2];
  const float* lam_ri   = (const float*)d_in[3];
  const float* B_ri     = (const float*)d_in[4];
  const float* Ct_ri    = (const float*)d_in[5];
  const float* Dp       = (const float*)d_in[6];
  const float* log_step = (const float*)d_in[7];
  float* out = (float*)d_out;

  char* wsb = (char*)d_ws;
  float2* tw    = (float2*)wsb;                                  // 32 KB
  float4* Kd    = (float4*)(wsb + NFFT * sizeof(float2));        // 8,396,800 B
  float2* atr   = (float2*)Kd;                                   // alias (dead before Kd written)
  float*  Ktime = (float*)(wsb + NFFT * sizeof(float2)
                               + (size_t)256 * REC_STRIDE * sizeof(float4)); // 4 MB

  twiddle_init<<<16, 256, 0, stream>>>(tw);
  s4_cauchy<<<dim3(DMODEL, 8), 256, 0, stream>>>(p_ri, q_ri, lam_ri, B_ri, Ct_ri,
                                                 log_step, atr);
  s4_fftK<<<DMODEL, 256, 0, stream>>>(atr, tw, Ktime);
  s4_pairB<<<DMODEL/2, 512, 0, stream>>>(Ktime, tw, Kd);
  s4_conv<<<dim3(DMODEL/2, NBATCH), 512, 0, stream>>>(u, Dp, tw, Kd, out);
}